// Round 3
// baseline (204.721 us; speedup 1.0000x reference)
//
#include <hip/hip_runtime.h>

typedef __attribute__((ext_vector_type(8))) short  short8;
typedef __attribute__((ext_vector_type(4))) float  floatx4;
typedef __attribute__((ext_vector_type(4))) int    intx4;

constexpr int DIN = 100;
constexpr int H   = 64;
constexpr int G   = 10;
constexpr int NH  = 5;
constexpr int MWG = 128;                 // rows per block (4 waves x 32 rows)
constexpr int HP  = 72;                  // hbuf pitch in halfwords: 144B rows, 16B-aligned
constexpr int PBP = 20;                  // pbuf pitch (floats): 2-way-free banks, 16B-aligned

// fragment counts in ws: dW0 (K=128 padded) 16; dW1 8; dbW 2; W0 5h*8=40
constexpr int NF_DW0 = 16, NF_DW1 = 8, NF_DBW = 2;
constexpr int NF_LIN = NF_DW0 + NF_DW1 + NF_DBW;     // 26
constexpr int NF_TOT = NF_LIN + 40;                  // 66

__device__ __forceinline__ unsigned short f2bf_rne(float f) {
    union { float f; unsigned u; } v{f};
    unsigned r = v.u + 0x7FFF + ((v.u >> 16) & 1);   // RNE
    return (unsigned short)(r >> 16);
}

// round-half-up pack of 8 floats -> short8 (bf16)
__device__ __forceinline__ short8 pack8(const float* f) {
    intx4 p;
    #pragma unroll
    for (int j = 0; j < 4; ++j) {
        unsigned a = __float_as_uint(f[2 * j])     + 0x8000u;
        unsigned b = __float_as_uint(f[2 * j + 1]) + 0x8000u;
        p[j] = (int)((b & 0xFFFF0000u) | (a >> 16));
    }
    union { intx4 i; short8 s; } u; u.i = p;
    return u.s;
}

// round-half-up pack of 2 floats -> one dword of 2 bf16 (same rounding as above)
__device__ __forceinline__ unsigned pack2bf(float a, float b) {
    unsigned ua = __float_as_uint(a) + 0x8000u;
    unsigned ub = __float_as_uint(b) + 0x8000u;
    return (ua >> 16) | (ub & 0xFFFF0000u);
}

__device__ __forceinline__ short8 ldfrag(const unsigned short* __restrict__ ws,
                                         int f, int lane) {
    return *(const short8*)(ws + (size_t)(f * 64 + lane) * 8);
}

// ---- pre-kernel: pack all weights as bf16 MFMA fragments into ws ----
// Layout note: lane holds W[k = (lane>>4)*8 + j][n = lane&15]. This is
// simultaneously the B-fragment of W and the A-fragment of W^T (the lane
// maps are mirror images) — the main kernel uses them as A-operands to
// compute transposed outputs h^T = W^T @ x^T.
__global__ __launch_bounds__(64) void pack_kernel(
    const float* __restrict__ dW0, const float* __restrict__ dW1,
    const float* __restrict__ dbW, const float* __restrict__ W0,
    unsigned short* __restrict__ ws)
{
    const int f = blockIdx.x;            // fragment id 0..65
    const int lane = threadIdx.x;
    const int q = lane >> 4, cl = lane & 15;
    float v[8];
    if (f < NF_DW0) {                    // dW0: K padded 100->128 with zeros
        int c = f >> 2, g = f & 3;
        #pragma unroll
        for (int j = 0; j < 8; ++j) {
            int k = c * 32 + q * 8 + j, n = g * 16 + cl;
            v[j] = (k < DIN) ? dW0[k * H + n] : 0.0f;
        }
    } else if (f < NF_DW0 + NF_DW1) {    // dW1: K=64
        int r = f - NF_DW0; int c = r >> 2, g = r & 3;
        #pragma unroll
        for (int j = 0; j < 8; ++j) {
            int k = c * 32 + q * 8 + j, n = g * 16 + cl;
            v[j] = dW1[k * H + n];
        }
    } else if (f < NF_LIN) {             // dbW: K=64, N=11 padded to 16
        int c = f - (NF_DW0 + NF_DW1);
        #pragma unroll
        for (int j = 0; j < 8; ++j) {
            int k = c * 32 + q * 8 + j, n = cl;
            v[j] = (n <= G) ? dbW[k * (G + 1) + n] : 0.0f;
        }
    } else {                             // W0: 5 heads, K=64
        int r = f - NF_LIN; int h = r >> 3; r &= 7; int c = r >> 2, g = r & 3;
        #pragma unroll
        for (int j = 0; j < 8; ++j) {
            int k = c * 32 + q * 8 + j, n = g * 16 + cl;
            v[j] = W0[(h * H + k) * H + n];
        }
    }
    short8 s;
    #pragma unroll
    for (int j = 0; j < 8; ++j) s[j] = (short)f2bf_rne(v[j]);
    *(short8*)(ws + (size_t)(f * 64 + lane) * 8) = s;
}

// ---- main kernel (all MFMAs operand-swapped: D = W^T @ x^T = h^T) ----
// C-layout after swap: thread (q,cl) holds h[batch=cl][hid = 4q+r] per tile
// -> contiguous-hid epilogues: b64 LDS writes, float4 param loads, 2-shfl
//    reductions, per-thread-uniform bucket predicate in the heads phase.
__global__ __launch_bounds__(256, 3) void drnet_mfma(
    const float* __restrict__ dosage, const float* __restrict__ x,
    const float* __restrict__ db0, const float* __restrict__ db1,
    const float* __restrict__ dbB,
    const float* __restrict__ tw0, const float* __restrict__ b0,
    const float* __restrict__ W1, const float* __restrict__ tw1,
    const float* __restrict__ b1,
    const unsigned short* __restrict__ wsfrag,
    float* __restrict__ outg, float* __restrict__ outq)
{
    __shared__ unsigned short hbuf[MWG * HP];    // 18432 B
    __shared__ float          pbuf[4][16][PBP];  // 5120 B: wave-private softmax scratch
    __shared__ int            perm[MWG];         // sorted pos -> row-in-block
    __shared__ float          tbuf[MWG];         // dosage in sorted order
    __shared__ unsigned char  bkbuf[MWG];        // bucket in sorted order
    __shared__ float          qbuf[MWG];         // Q in original row order
    __shared__ int            hist[NH];
    __shared__ int            offs[NH];

    const int tid  = threadIdx.x;
    const int wave = tid >> 6, lane = tid & 63;
    const int q = lane >> 4, cl = lane & 15;
    const int rowbase = blockIdx.x * MWG + wave * 32;   // this wave's 32 rows
    unsigned short* hb = hbuf + wave * 32 * HP;

    // ================= phase 0: counting sort by dosage bucket =================
    if (tid < NH) hist[tid] = 0;
    __syncthreads();
    {
        float t8[2][4];
        int   bk8[2][4];
        #pragma unroll
        for (int mt = 0; mt < 2; ++mt) {
            floatx4 tv = *(const floatx4*)(dosage + rowbase + mt * 16 + 4 * q);
            #pragma unroll
            for (int r = 0; r < 4; ++r) {
                float t = tv[r];
                t8[mt][r] = t;
                int bk = (int)floorf(t * (float)NH);
                bk8[mt][r] = min(max(bk, 0), NH - 1);
            }
        }
        if (cl == 0) {
            #pragma unroll
            for (int mt = 0; mt < 2; ++mt)
                #pragma unroll
                for (int r = 0; r < 4; ++r)
                    atomicAdd(&hist[bk8[mt][r]], 1);
        }
        __syncthreads();
        if (tid == 0) {
            int a = 0;
            #pragma unroll
            for (int h = 0; h < NH; ++h) { offs[h] = a; a += hist[h]; }
        }
        __syncthreads();
        if (cl == 0) {
            #pragma unroll
            for (int mt = 0; mt < 2; ++mt)
                #pragma unroll
                for (int r = 0; r < 4; ++r) {
                    const int bk  = bk8[mt][r];
                    const int pos = atomicAdd(&offs[bk], 1);
                    perm[pos]  = wave * 32 + mt * 16 + 4 * q + r;
                    tbuf[pos]  = t8[mt][r];
                    bkbuf[pos] = (unsigned char)bk;
                }
        }
        // visibility of perm/tbuf/bkbuf guaranteed by the pre-heads barrier
    }

    // ====== layer 1: h1^T = dW0^T @ x^T (swapped); epilogue writes row-major hb ======
    #pragma unroll 1
    for (int mt = 0; mt < 2; ++mt) {
        short8 a1[4];                    // x^T B-fragments: lane holds x[cl][k-chunk]
        const float* xr = x + (size_t)(rowbase + mt * 16 + cl) * DIN;
        #pragma unroll
        for (int cch = 0; cch < 4; ++cch) {
            float f[8];
            if (cch < 3) {
                floatx4 u0 = *(const floatx4*)(xr + cch * 32 + q * 8);
                floatx4 u1 = *(const floatx4*)(xr + cch * 32 + q * 8 + 4);
                f[0]=u0.x; f[1]=u0.y; f[2]=u0.z; f[3]=u0.w;
                f[4]=u1.x; f[5]=u1.y; f[6]=u1.z; f[7]=u1.w;
            } else {
                if (q == 0) {
                    floatx4 u0 = *(const floatx4*)(xr + 96);
                    f[0]=u0.x; f[1]=u0.y; f[2]=u0.z; f[3]=u0.w;
                    f[4]=f[5]=f[6]=f[7]=0.0f;
                } else {
                    #pragma unroll
                    for (int j = 0; j < 8; ++j) f[j] = 0.0f;
                }
            }
            a1[cch] = pack8(f);
        }
        floatx4 acc[4];                  // acc[g]: hid-tile g, thread holds hid 4q+r
        #pragma unroll
        for (int g = 0; g < 4; ++g) acc[g] = (floatx4)0.0f;
        #pragma unroll
        for (int cch = 0; cch < 4; ++cch)
            #pragma unroll
            for (int g = 0; g < 4; ++g) {
                short8 bf = ldfrag(wsfrag, cch * 4 + g, lane);
                acc[g] = __builtin_amdgcn_mfma_f32_16x16x32_bf16(bf, a1[cch], acc[g], 0, 0, 0);
            }
        #pragma unroll
        for (int g = 0; g < 4; ++g) {
            floatx4 bias = *(const floatx4*)(db0 + g * 16 + 4 * q);
            float v0 = fmaxf(acc[g][0] + bias[0], 0.0f);
            float v1 = fmaxf(acc[g][1] + bias[1], 0.0f);
            float v2 = fmaxf(acc[g][2] + bias[2], 0.0f);
            float v3 = fmaxf(acc[g][3] + bias[3], 0.0f);
            *(uint2*)(hb + (size_t)(mt * 16 + cl) * HP + g * 16 + 4 * q) =
                make_uint2(pack2bf(v0, v1), pack2bf(v2, v3));
        }
    }
    // wave-private rows + in-order DS pipe: no barrier needed

    // ====== layer 2: h2^T = dW1^T @ h1^T (swapped) ======
    #pragma unroll 1
    for (int mt = 0; mt < 2; ++mt) {
        short8 a2[2];                    // h1^T B-frags: lane reads its row cl
        #pragma unroll
        for (int cch = 0; cch < 2; ++cch)
            a2[cch] = *(const short8*)(hb + (mt * 16 + cl) * HP + cch * 32 + q * 8);
        floatx4 acc[4];
        #pragma unroll
        for (int g = 0; g < 4; ++g) acc[g] = (floatx4)0.0f;
        #pragma unroll
        for (int cch = 0; cch < 2; ++cch)
            #pragma unroll
            for (int g = 0; g < 4; ++g) {
                short8 bf = ldfrag(wsfrag, NF_DW0 + cch * 4 + g, lane);
                acc[g] = __builtin_amdgcn_mfma_f32_16x16x32_bf16(bf, a2[cch], acc[g], 0, 0, 0);
            }
        #pragma unroll
        for (int g = 0; g < 4; ++g) {
            floatx4 bias = *(const floatx4*)(db1 + g * 16 + 4 * q);
            float v0 = fmaxf(acc[g][0] + bias[0], 0.0f);
            float v1 = fmaxf(acc[g][1] + bias[1], 0.0f);
            float v2 = fmaxf(acc[g][2] + bias[2], 0.0f);
            float v3 = fmaxf(acc[g][3] + bias[3], 0.0f);
            *(uint2*)(hb + (size_t)(mt * 16 + cl) * HP + g * 16 + 4 * q) =
                make_uint2(pack2bf(v0, v1), pack2bf(v2, v3));
        }
    }

    // h2^T B-fragments for own rows (density; heads re-gather sorted rows)
    short8 af[2][2];
    #pragma unroll
    for (int mt = 0; mt < 2; ++mt)
        #pragma unroll
        for (int cch = 0; cch < 2; ++cch)
            af[mt][cch] = *(const short8*)(hb + (mt * 16 + cl) * HP + cch * 32 + q * 8);

    // ====== density: p^T = softmax(dbW^T @ h2^T + dbB) + interp ======
    // thread holds logits for grid dims 4q+r of batch row cl
    {
        floatx4 accd[2];
        accd[0] = (floatx4)0.0f; accd[1] = (floatx4)0.0f;
        #pragma unroll
        for (int cch = 0; cch < 2; ++cch) {
            short8 bf = ldfrag(wsfrag, NF_DW0 + NF_DW1 + cch, lane);
            #pragma unroll
            for (int mt = 0; mt < 2; ++mt)
                accd[mt] = __builtin_amdgcn_mfma_f32_16x16x32_bf16(bf, af[mt][cch], accd[mt], 0, 0, 0);
        }
        #pragma unroll
        for (int mt = 0; mt < 2; ++mt) {
            floatx4 ev;
            float sp = 0.0f;
            #pragma unroll
            for (int r = 0; r < 4; ++r) {
                const int gd = 4 * q + r;
                float e = (gd <= G) ? __expf(accd[mt][r] + dbB[gd]) : 0.0f;
                ev[r] = e;
                sp += e;
            }
            float s = sp;
            s += __shfl_xor(s, 16); s += __shfl_xor(s, 32);   // sum over grid dims
            // exchange e across q-groups via wave-private LDS scratch
            *(floatx4*)(&pbuf[wave][cl][4 * q]) = ev;
            const float t  = dosage[rowbase + mt * 16 + cl];
            const float tB = t * (float)G;
            const float U  = ceilf(tB);
            const float inter = 1.0f - (U - tB);
            int Ui = (int)U; int Li = Ui - 1; if (Li < 0) Li = 0;
            const float pL = pbuf[wave][cl][Li];
            const float pU = pbuf[wave][cl][Ui];
            if (q == 0)
                outg[rowbase + mt * 16 + cl] = (pL + (pU - pL) * inter) / s;
        }
    }

    // ====== heads: h0^T = W0^T @ h2^T on sorted tiles; per-thread bucket ======
    __syncthreads();                 // all h2 in hbuf + perm/tbuf/bkbuf visible
    #pragma unroll 1
    for (int mt = 0; mt < 2; ++mt) {
        const int base = (wave * 2 + mt) * 16;       // my sorted 16-row tile
        const int prow = perm[base + cl];            // thread's batch row = cl
        short8 ag[2];
        ag[0] = *(const short8*)(hbuf + prow * HP + q * 8);
        ag[1] = *(const short8*)(hbuf + prow * HP + 32 + q * 8);
        const float tme  = tbuf[base + cl];
        const int   bkme = bkbuf[base + cl];
        const int   blo  = bkbuf[base], bhi = bkbuf[base + 15];   // contiguous
        float qp = 0.0f;
        #pragma unroll 1
        for (int h = blo; h <= bhi; ++h) {
            floatx4 acch[4];
            #pragma unroll
            for (int g = 0; g < 4; ++g) acch[g] = (floatx4)0.0f;
            #pragma unroll
            for (int cch = 0; cch < 2; ++cch)
                #pragma unroll
                for (int g = 0; g < 4; ++g) {
                    short8 bf = ldfrag(wsfrag, NF_LIN + h * 8 + cch * 4 + g, lane);
                    acch[g] = __builtin_amdgcn_mfma_f32_16x16x32_bf16(bf, ag[cch], acch[g], 0, 0, 0);
                }
            if (bkme == h) {             // exec-masked: total epilogue ~= one pass
                #pragma unroll
                for (int g = 0; g < 4; ++g) {
                    const int off = h * H + g * 16 + 4 * q;
                    floatx4 tw0v = *(const floatx4*)(tw0 + off);
                    floatx4 b0v  = *(const floatx4*)(b0  + off);
                    floatx4 w1v  = *(const floatx4*)(W1  + off);
                    #pragma unroll
                    for (int r = 0; r < 4; ++r)
                        qp += fmaxf(acch[g][r] + tme * tw0v[r] + b0v[r], 0.0f) * w1v[r];
                }
            }
        }
        qp += __shfl_xor(qp, 16); qp += __shfl_xor(qp, 32);   // sum over hid
        if (q == 0)
            qbuf[prow] = qp + tme * tw1[bkme] + b1[bkme];
    }

    // coalesced Q store (qbuf is in original row order)
    __syncthreads();
    if (tid < MWG / 4) {
        floatx4 v = *(const floatx4*)(qbuf + tid * 4);
        *(floatx4*)(outq + blockIdx.x * MWG + tid * 4) = v;
    }
}

extern "C" void kernel_launch(void* const* d_in, const int* in_sizes, int n_in,
                              void* d_out, int out_size, void* d_ws, size_t ws_size,
                              hipStream_t stream) {
    const float* dosage = (const float*)d_in[0];
    const float* x      = (const float*)d_in[1];
    const float* dW0    = (const float*)d_in[2];
    const float* db0    = (const float*)d_in[3];
    const float* dW1    = (const float*)d_in[4];
    const float* db1    = (const float*)d_in[5];
    const float* dbW    = (const float*)d_in[6];
    const float* dbB    = (const float*)d_in[7];
    const float* W0     = (const float*)d_in[8];
    const float* tw0    = (const float*)d_in[9];
    const float* b0     = (const float*)d_in[10];
    const float* W1     = (const float*)d_in[11];
    const float* tw1    = (const float*)d_in[12];
    const float* b1     = (const float*)d_in[13];

    const int Btot = in_sizes[0];
    float* outg = (float*)d_out;
    float* outq = outg + Btot;
    unsigned short* ws = (unsigned short*)d_ws;

    pack_kernel<<<NF_TOT, 64, 0, stream>>>(dW0, dW1, dbW, W0, ws);
    drnet_mfma<<<Btot / MWG, 256, 0, stream>>>(dosage, x, db0, db1, dbB,
                                               tw0, b0, W1, tw1, b1,
                                               ws, outg, outq);
}

// Round 5
// 198.660 us; speedup vs baseline: 1.0305x; 1.0305x over previous
//
#include <hip/hip_runtime.h>

typedef __attribute__((ext_vector_type(8))) short  short8;
typedef __attribute__((ext_vector_type(4))) float  floatx4;
typedef __attribute__((ext_vector_type(4))) int    intx4;

constexpr int DIN = 100;
constexpr int H   = 64;
constexpr int G   = 10;
constexpr int NH  = 5;
constexpr int MWG = 128;                 // rows per block (4 waves x 32 rows)
constexpr int HP  = 72;                  // hbuf pitch in halfwords: 144B rows, 16B-aligned
constexpr int PBP = 20;                  // pbuf pitch (floats): 2-way-free banks, 16B-aligned

// fragment counts in ws: dW0 (K=128 padded) 16; dW1 8; dbW 2; W0 5h*8=40
constexpr int NF_DW0 = 16, NF_DW1 = 8, NF_DBW = 2;
constexpr int NF_LIN = NF_DW0 + NF_DW1 + NF_DBW;     // 26
constexpr int NF_TOT = NF_LIN + 40;                  // 66

__device__ __forceinline__ unsigned short f2bf_rne(float f) {
    union { float f; unsigned u; } v{f};
    unsigned r = v.u + 0x7FFF + ((v.u >> 16) & 1);   // RNE
    return (unsigned short)(r >> 16);
}

// round-half-up pack of 8 floats -> short8 (bf16)
__device__ __forceinline__ short8 pack8(const float* f) {
    intx4 p;
    #pragma unroll
    for (int j = 0; j < 4; ++j) {
        unsigned a = __float_as_uint(f[2 * j])     + 0x8000u;
        unsigned b = __float_as_uint(f[2 * j + 1]) + 0x8000u;
        p[j] = (int)((b & 0xFFFF0000u) | (a >> 16));
    }
    union { intx4 i; short8 s; } u; u.i = p;
    return u.s;
}

// round-half-up pack of 2 floats -> one dword of 2 bf16 (same rounding as above)
__device__ __forceinline__ unsigned pack2bf(float a, float b) {
    unsigned ua = __float_as_uint(a) + 0x8000u;
    unsigned ub = __float_as_uint(b) + 0x8000u;
    return (ua >> 16) | (ub & 0xFFFF0000u);
}

__device__ __forceinline__ short8 ldfrag(const unsigned short* __restrict__ ws,
                                         int f, int lane) {
    return *(const short8*)(ws + (size_t)(f * 64 + lane) * 8);
}

// lgkm-only barrier: does NOT drain vmcnt, so prefetched global loads stay
// in flight across it (plain __syncthreads drains vmcnt(0) and would stall).
// DS atomics are lgkmcnt-counted and LDS is CU-coherent, so this is a
// sufficient fence for LDS-only communication (m201-template pattern).
__device__ __forceinline__ void bar_lgkm() {
    asm volatile("s_waitcnt lgkmcnt(0)" ::: "memory");
    __builtin_amdgcn_s_barrier();
    asm volatile("" ::: "memory");
}

// ---- pre-kernel: pack all weights as bf16 MFMA fragments into ws ----
// Layout note: lane holds W[k = (lane>>4)*8 + j][n = lane&15]. This is
// simultaneously the B-fragment of W and the A-fragment of W^T — the main
// kernel uses them as A-operands to compute transposed outputs h^T.
__global__ __launch_bounds__(64) void pack_kernel(
    const float* __restrict__ dW0, const float* __restrict__ dW1,
    const float* __restrict__ dbW, const float* __restrict__ W0,
    unsigned short* __restrict__ ws)
{
    const int f = blockIdx.x;            // fragment id 0..65
    const int lane = threadIdx.x;
    const int q = lane >> 4, cl = lane & 15;
    float v[8];
    if (f < NF_DW0) {                    // dW0: K padded 100->128 with zeros
        int c = f >> 2, g = f & 3;
        #pragma unroll
        for (int j = 0; j < 8; ++j) {
            int k = c * 32 + q * 8 + j, n = g * 16 + cl;
            v[j] = (k < DIN) ? dW0[k * H + n] : 0.0f;
        }
    } else if (f < NF_DW0 + NF_DW1) {    // dW1: K=64
        int r = f - NF_DW0; int c = r >> 2, g = r & 3;
        #pragma unroll
        for (int j = 0; j < 8; ++j) {
            int k = c * 32 + q * 8 + j, n = g * 16 + cl;
            v[j] = dW1[k * H + n];
        }
    } else if (f < NF_LIN) {             // dbW: K=64, N=11 padded to 16
        int c = f - (NF_DW0 + NF_DW1);
        #pragma unroll
        for (int j = 0; j < 8; ++j) {
            int k = c * 32 + q * 8 + j, n = cl;
            v[j] = (n <= G) ? dbW[k * (G + 1) + n] : 0.0f;
        }
    } else {                             // W0: 5 heads, K=64
        int r = f - NF_LIN; int h = r >> 3; r &= 7; int c = r >> 2, g = r & 3;
        #pragma unroll
        for (int j = 0; j < 8; ++j) {
            int k = c * 32 + q * 8 + j, n = g * 16 + cl;
            v[j] = W0[(h * H + k) * H + n];
        }
    }
    short8 s;
    #pragma unroll
    for (int j = 0; j < 8; ++j) s[j] = (short)f2bf_rne(v[j]);
    *(short8*)(ws + (size_t)(f * 64 + lane) * 8) = s;
}

// ---- main kernel (operand-swapped MFMAs: D = W^T @ x^T = h^T) ----
// Pipeline: issue all x/dosage global loads -> counting sort (lgkm-only
// barriers; x latency hides under it) -> layer1 (both mt merged, 8 acc
// chains) -> layer2 -> density -> full barrier -> heads on sorted tiles.
__global__ __launch_bounds__(256, 3) void drnet_mfma(
    const float* __restrict__ dosage, const float* __restrict__ x,
    const float* __restrict__ db0, const float* __restrict__ db1,
    const float* __restrict__ dbB,
    const float* __restrict__ tw0, const float* __restrict__ b0,
    const float* __restrict__ W1, const float* __restrict__ tw1,
    const float* __restrict__ b1,
    const unsigned short* __restrict__ wsfrag,
    float* __restrict__ outg, float* __restrict__ outq)
{
    __shared__ unsigned short hbuf[MWG * HP];    // 18432 B
    __shared__ float          pbuf[4][16][PBP];  // 5120 B: wave-private softmax scratch
    __shared__ int            perm[MWG];         // sorted pos -> row-in-block
    __shared__ float          tbuf[MWG];         // dosage in sorted order
    __shared__ unsigned char  bkbuf[MWG];        // bucket in sorted order
    __shared__ float          qbuf[MWG];         // Q in original row order
    __shared__ int            hist[NH];
    __shared__ int            offs[NH];

    const int tid  = threadIdx.x;
    const int wave = tid >> 6, lane = tid & 63;
    const int q = lane >> 4, cl = lane & 15;
    const int rowbase = blockIdx.x * MWG + wave * 32;   // this wave's 32 rows
    unsigned short* hb = hbuf + wave * 32 * HP;

    // ======= phase -1: issue ALL global loads for sort + layer1 up front =======
    floatx4 tvs[2];
    #pragma unroll
    for (int mt = 0; mt < 2; ++mt)
        tvs[mt] = *(const floatx4*)(dosage + rowbase + mt * 16 + 4 * q);
    floatx4 xv[2][7];
    #pragma unroll
    for (int mt = 0; mt < 2; ++mt) {
        const float* xr = x + (size_t)(rowbase + mt * 16 + cl) * DIN;
        #pragma unroll
        for (int cch = 0; cch < 3; ++cch) {
            xv[mt][2 * cch]     = *(const floatx4*)(xr + cch * 32 + q * 8);
            xv[mt][2 * cch + 1] = *(const floatx4*)(xr + cch * 32 + q * 8 + 4);
        }
        xv[mt][6] = (q == 0) ? *(const floatx4*)(xr + 96) : (floatx4)0.0f;
    }

    // ================= phase 0: counting sort by dosage bucket =================
    // x loads remain in flight across all of this (lgkm-only barriers).
    if (tid < NH) hist[tid] = 0;
    bar_lgkm();
    {
        float t8[2][4];
        int   bk8[2][4];
        #pragma unroll
        for (int mt = 0; mt < 2; ++mt)
            #pragma unroll
            for (int r = 0; r < 4; ++r) {
                float t = tvs[mt][r];
                t8[mt][r] = t;
                int bk = (int)floorf(t * (float)NH);
                bk8[mt][r] = min(max(bk, 0), NH - 1);
            }
        if (cl == 0) {
            #pragma unroll
            for (int mt = 0; mt < 2; ++mt)
                #pragma unroll
                for (int r = 0; r < 4; ++r)
                    atomicAdd(&hist[bk8[mt][r]], 1);
        }
        bar_lgkm();
        if (tid == 0) {
            int a = 0;
            #pragma unroll
            for (int h = 0; h < NH; ++h) { offs[h] = a; a += hist[h]; }
        }
        bar_lgkm();
        if (cl == 0) {
            #pragma unroll
            for (int mt = 0; mt < 2; ++mt)
                #pragma unroll
                for (int r = 0; r < 4; ++r) {
                    const int bk  = bk8[mt][r];
                    const int pos = atomicAdd(&offs[bk], 1);
                    perm[pos]  = wave * 32 + mt * 16 + 4 * q + r;
                    tbuf[pos]  = t8[mt][r];
                    bkbuf[pos] = (unsigned char)bk;
                }
        }
        // visibility of perm/tbuf/bkbuf guaranteed by the pre-heads barrier
    }

    // ====== layer 1: h1^T = dW0^T @ x^T, both mt merged (8 acc chains) ======
    {
        short8 a1[2][4];
        #pragma unroll
        for (int mt = 0; mt < 2; ++mt)
            #pragma unroll
            for (int cch = 0; cch < 4; ++cch) {
                float f[8];
                if (cch < 3) {
                    #pragma unroll
                    for (int j = 0; j < 4; ++j) {
                        f[j]     = xv[mt][2 * cch][j];
                        f[4 + j] = xv[mt][2 * cch + 1][j];
                    }
                } else {
                    #pragma unroll
                    for (int j = 0; j < 4; ++j) {
                        f[j]     = xv[mt][6][j];
                        f[4 + j] = 0.0f;
                    }
                }
                a1[mt][cch] = pack8(f);
            }
        floatx4 acc[2][4];
        #pragma unroll
        for (int mt = 0; mt < 2; ++mt)
            #pragma unroll
            for (int g = 0; g < 4; ++g) acc[mt][g] = (floatx4)0.0f;
        #pragma unroll
        for (int cch = 0; cch < 4; ++cch)
            #pragma unroll
            for (int g = 0; g < 4; ++g) {
                short8 bf = ldfrag(wsfrag, cch * 4 + g, lane);   // shared by both mt
                acc[0][g] = __builtin_amdgcn_mfma_f32_16x16x32_bf16(bf, a1[0][cch], acc[0][g], 0, 0, 0);
                acc[1][g] = __builtin_amdgcn_mfma_f32_16x16x32_bf16(bf, a1[1][cch], acc[1][g], 0, 0, 0);
            }
        #pragma unroll
        for (int mt = 0; mt < 2; ++mt)
            #pragma unroll
            for (int g = 0; g < 4; ++g) {
                floatx4 bias = *(const floatx4*)(db0 + g * 16 + 4 * q);
                float v0 = fmaxf(acc[mt][g][0] + bias[0], 0.0f);
                float v1 = fmaxf(acc[mt][g][1] + bias[1], 0.0f);
                float v2 = fmaxf(acc[mt][g][2] + bias[2], 0.0f);
                float v3 = fmaxf(acc[mt][g][3] + bias[3], 0.0f);
                *(uint2*)(hb + (size_t)(mt * 16 + cl) * HP + g * 16 + 4 * q) =
                    make_uint2(pack2bf(v0, v1), pack2bf(v2, v3));
            }
    }
    // wave-private rows + in-order DS pipe: no barrier needed

    // ====== layer 2: h2^T = dW1^T @ h1^T, both mt merged ======
    {
        short8 a2[2][2];
        #pragma unroll
        for (int mt = 0; mt < 2; ++mt)
            #pragma unroll
            for (int cch = 0; cch < 2; ++cch)
                a2[mt][cch] = *(const short8*)(hb + (mt * 16 + cl) * HP + cch * 32 + q * 8);
        floatx4 acc[2][4];
        #pragma unroll
        for (int mt = 0; mt < 2; ++mt)
            #pragma unroll
            for (int g = 0; g < 4; ++g) acc[mt][g] = (floatx4)0.0f;
        #pragma unroll
        for (int cch = 0; cch < 2; ++cch)
            #pragma unroll
            for (int g = 0; g < 4; ++g) {
                short8 bf = ldfrag(wsfrag, NF_DW0 + cch * 4 + g, lane);
                acc[0][g] = __builtin_amdgcn_mfma_f32_16x16x32_bf16(bf, a2[0][cch], acc[0][g], 0, 0, 0);
                acc[1][g] = __builtin_amdgcn_mfma_f32_16x16x32_bf16(bf, a2[1][cch], acc[1][g], 0, 0, 0);
            }
        #pragma unroll
        for (int mt = 0; mt < 2; ++mt)
            #pragma unroll
            for (int g = 0; g < 4; ++g) {
                floatx4 bias = *(const floatx4*)(db1 + g * 16 + 4 * q);
                float v0 = fmaxf(acc[mt][g][0] + bias[0], 0.0f);
                float v1 = fmaxf(acc[mt][g][1] + bias[1], 0.0f);
                float v2 = fmaxf(acc[mt][g][2] + bias[2], 0.0f);
                float v3 = fmaxf(acc[mt][g][3] + bias[3], 0.0f);
                *(uint2*)(hb + (size_t)(mt * 16 + cl) * HP + g * 16 + 4 * q) =
                    make_uint2(pack2bf(v0, v1), pack2bf(v2, v3));
            }
    }

    // ====== density: p^T = softmax(dbW^T @ h2^T + dbB) + interp ======
    // thread holds logits for grid dims 4q+r of batch row cl
    {
        float tden[2];                   // issue dosage loads before the MFMAs
        #pragma unroll
        for (int mt = 0; mt < 2; ++mt)
            tden[mt] = dosage[rowbase + mt * 16 + cl];
        short8 af[2][2];
        #pragma unroll
        for (int mt = 0; mt < 2; ++mt)
            #pragma unroll
            for (int cch = 0; cch < 2; ++cch)
                af[mt][cch] = *(const short8*)(hb + (mt * 16 + cl) * HP + cch * 32 + q * 8);
        floatx4 accd[2];
        accd[0] = (floatx4)0.0f; accd[1] = (floatx4)0.0f;
        #pragma unroll
        for (int cch = 0; cch < 2; ++cch) {
            short8 bf = ldfrag(wsfrag, NF_DW0 + NF_DW1 + cch, lane);
            #pragma unroll
            for (int mt = 0; mt < 2; ++mt)
                accd[mt] = __builtin_amdgcn_mfma_f32_16x16x32_bf16(bf, af[mt][cch], accd[mt], 0, 0, 0);
        }
        #pragma unroll
        for (int mt = 0; mt < 2; ++mt) {
            floatx4 ev;
            float sp = 0.0f;
            #pragma unroll
            for (int r = 0; r < 4; ++r) {
                const int gd = 4 * q + r;
                float e = (gd <= G) ? __expf(accd[mt][r] + dbB[gd]) : 0.0f;
                ev[r] = e;
                sp += e;
            }
            float s = sp;
            s += __shfl_xor(s, 16); s += __shfl_xor(s, 32);   // sum over grid dims
            // exchange e across q-groups via wave-private LDS scratch
            *(floatx4*)(&pbuf[wave][cl][4 * q]) = ev;
            const float t  = tden[mt];
            const float tB = t * (float)G;
            const float U  = ceilf(tB);
            const float inter = 1.0f - (U - tB);
            int Ui = (int)U; int Li = Ui - 1; if (Li < 0) Li = 0;
            const float pL = pbuf[wave][cl][Li];
            const float pU = pbuf[wave][cl][Ui];
            if (q == 0)
                outg[rowbase + mt * 16 + cl] = (pL + (pU - pL) * inter) / s;
        }
    }

    // ====== heads: h0^T = W0^T @ h2^T on sorted tiles; per-thread bucket ======
    __syncthreads();                 // all h2 in hbuf + perm/tbuf/bkbuf visible
    {
        short8 ag[2][2];
        int    prow[2], bkme[2], blo[2], bhi[2];
        float  tme[2];
        #pragma unroll
        for (int mt = 0; mt < 2; ++mt) {
            const int base = (wave * 2 + mt) * 16;   // my sorted 16-row tile
            prow[mt] = perm[base + cl];              // thread's batch row = cl
            ag[mt][0] = *(const short8*)(hbuf + prow[mt] * HP + q * 8);
            ag[mt][1] = *(const short8*)(hbuf + prow[mt] * HP + 32 + q * 8);
            tme[mt]  = tbuf[base + cl];
            bkme[mt] = bkbuf[base + cl];
            blo[mt]  = bkbuf[base];
            bhi[mt]  = bkbuf[base + 15];             // contiguous bucket range
        }
        #pragma unroll
        for (int mt = 0; mt < 2; ++mt) {
            float qp = 0.0f;
            #pragma unroll 1
            for (int h = blo[mt]; h <= bhi[mt]; ++h) {
                floatx4 acch[4];
                #pragma unroll
                for (int g = 0; g < 4; ++g) acch[g] = (floatx4)0.0f;
                #pragma unroll
                for (int cch = 0; cch < 2; ++cch)
                    #pragma unroll
                    for (int g = 0; g < 4; ++g) {
                        short8 bf = ldfrag(wsfrag, NF_LIN + h * 8 + cch * 4 + g, lane);
                        acch[g] = __builtin_amdgcn_mfma_f32_16x16x32_bf16(bf, ag[mt][cch], acch[g], 0, 0, 0);
                    }
                if (bkme[mt] == h) {     // exec-masked: total epilogue ~= one pass
                    #pragma unroll
                    for (int g = 0; g < 4; ++g) {
                        const int off = h * H + g * 16 + 4 * q;
                        floatx4 tw0v = *(const floatx4*)(tw0 + off);
                        floatx4 b0v  = *(const floatx4*)(b0  + off);
                        floatx4 w1v  = *(const floatx4*)(W1  + off);
                        #pragma unroll
                        for (int r = 0; r < 4; ++r)
                            qp += fmaxf(acch[g][r] + tme[mt] * tw0v[r] + b0v[r], 0.0f) * w1v[r];
                    }
                }
            }
            qp += __shfl_xor(qp, 16); qp += __shfl_xor(qp, 32);   // sum over hid
            if (q == 0)
                qbuf[prow[mt]] = qp + tme[mt] * tw1[bkme[mt]] + b1[bkme[mt]];
        }
    }

    // coalesced Q store (qbuf is in original row order)
    __syncthreads();
    if (tid < MWG / 4) {
        floatx4 v = *(const floatx4*)(qbuf + tid * 4);
        *(floatx4*)(outq + blockIdx.x * MWG + tid * 4) = v;
    }
}

extern "C" void kernel_launch(void* const* d_in, const int* in_sizes, int n_in,
                              void* d_out, int out_size, void* d_ws, size_t ws_size,
                              hipStream_t stream) {
    const float* dosage = (const float*)d_in[0];
    const float* x      = (const float*)d_in[1];
    const float* dW0    = (const float*)d_in[2];
    const float* db0    = (const float*)d_in[3];
    const float* dW1    = (const float*)d_in[4];
    const float* db1    = (const float*)d_in[5];
    const float* dbW    = (const float*)d_in[6];
    const float* dbB    = (const float*)d_in[7];
    const float* W0     = (const float*)d_in[8];
    const float* tw0    = (const float*)d_in[9];
    const float* b0     = (const float*)d_in[10];
    const float* W1     = (const float*)d_in[11];
    const float* tw1    = (const float*)d_in[12];
    const float* b1     = (const float*)d_in[13];

    const int Btot = in_sizes[0];
    float* outg = (float*)d_out;
    float* outq = outg + Btot;
    unsigned short* ws = (unsigned short*)d_ws;

    pack_kernel<<<NF_TOT, 64, 0, stream>>>(dW0, dW1, dbW, W0, ws);
    drnet_mfma<<<Btot / MWG, 256, 0, stream>>>(dosage, x, db0, db1, dbB,
                                               tw0, b0, W1, tw1, b1,
                                               ws, outg, outq);
}